// Round 1
// baseline (4787.796 us; speedup 1.0000x reference)
//
#include <hip/hip_runtime.h>
#include <math.h>

#define HH    128
#define GHN   9
#define GWN   9
#define BATCH 4096
#define NCELL 81
#define MSAMP 16
#define NBLK  (BATCH / MSAMP)   // 256
#define CS    20                // comb row stride in floats (16B-aligned rows, bank spread)
#define EPSF  1e-5f

__device__ __forceinline__ float rcp_fast(float x) { return __builtin_amdgcn_rcpf(x); }
__device__ __forceinline__ float rsq_fast(float x) { return __builtin_amdgcn_rsqf(x); }
__device__ __forceinline__ float sigm(float x)     { return rcp_fast(1.f + __expf(-x)); }
__device__ __forceinline__ float tanh_fast(float x) {
    float ax = fabsf(x);
    float t  = __expf(-2.f * ax);
    float r  = (1.f - t) * rcp_fast(1.f + t);
    return (x < 0.f) ? -r : r;
}
__device__ __forceinline__ float f4c(const float4& v, int c) {
    switch (c) { case 0: return v.x; case 1: return v.y; case 2: return v.z; default: return v.w; }
}

// ---------------------------------------------------------------------------
// Weight transposes into kk-blocked float4 layouts:
//   whT/wcT : [81][96][128][4]  (dst[k][kb][r][c] = Wh[k][r][4kb+c])
//   whhT    : [81][32][512][4]  (dst[k][kb][o][c] = W_hh[k][o][4kb+c])
// ---------------------------------------------------------------------------
__global__ __launch_bounds__(256)
void k_transpose(const float* __restrict__ Wh, const float* __restrict__ Wc,
                 const float* __restrict__ Whh,
                 float* __restrict__ whT, float* __restrict__ wcT,
                 float* __restrict__ whhT)
{
    const int n1 = 81 * 96 * 128;   // float4 count for Wh/Wc
    const int n2 = 81 * 32 * 512;   // float4 count for Whh
    int gid    = blockIdx.x * blockDim.x + threadIdx.x;
    int stride = gridDim.x * blockDim.x;
    for (int d = gid; d < n1; d += stride) {
        int r  = d & 127;
        int t  = d >> 7;          // k*96 + kb
        int kb = t % 96;
        int k  = t / 96;
        int s  = (k * 128 + r) * 96 + kb;
        ((float4*)whT)[d] = ((const float4*)Wh)[s];
        ((float4*)wcT)[d] = ((const float4*)Wc)[s];
    }
    for (int d = gid; d < n2; d += stride) {
        int o  = d & 511;
        int t  = d >> 9;          // k*32 + kb
        int kb = t & 31;
        int k  = t >> 5;
        int s  = (k * 512 + o) * 32 + kb;
        ((float4*)whhT)[d] = ((const float4*)Whh)[s];
    }
}

// ---------------------------------------------------------------------------
// Persistent lattice kernel: 256 blocks x 16 samples, loops over 81 cells.
// comb layout: [384 rows][stride CS=20], element (kk, m) at kk*CS + m.
//   rows   0..127 : left  (becomes h_new after each cell)
//   rows 128..255 : up    (from global row buffer)
//   rows 256..383 : prev  (h_grid0/c_grid0)
// ---------------------------------------------------------------------------
__global__ __launch_bounds__(256)
void k_lattice(const float* __restrict__ x, const float* __restrict__ h_ext,
               const float* __restrict__ c_ext, const float* __restrict__ h_g0,
               const float* __restrict__ c_g0,
               const float* __restrict__ whT, const float* __restrict__ wcT,
               const float* __restrict__ whhT,
               const float* __restrict__ bh, const float* __restrict__ bc,
               const float* __restrict__ lnh_g, const float* __restrict__ lnh_b,
               const float* __restrict__ lnc_g, const float* __restrict__ lnc_b,
               const float* __restrict__ W_ih, const float* __restrict__ b_ih,
               const float* __restrict__ b_hh,
               float* __restrict__ hrowB, float* __restrict__ crowB,
               float* __restrict__ zout)
{
    __shared__ float combH[384 * CS];
    __shared__ float combC[384 * CS];
    __shared__ float xv[MSAMP];

    const int t    = threadIdx.x;
    const int base = blockIdx.x * MSAMP;

    // pre-LN matmul roles: r-pair {rs, rs+64}, m-group of 4
    const int rs  = t & 63;
    const int mg  = t >> 6;        // 0..3 (== wave id)
    const int m0a = mg * 4;

    // gates roles: feature q, m-group of 8
    const int q   = t & 127;
    const int mg2 = t >> 7;        // 0..1
    const int m0b = mg2 * 8;

    // build roles
    const int hp16 = t & 15;
    const int mm   = t >> 4;       // 0..15 (sample)

    for (int i = 0; i < GHN; ++i) {
      for (int j = 0; j < GWN; ++j) {
        const int k = i * GWN + j;

        // ------------------ build phase ------------------
        if (t < MSAMP) xv[t] = x[(size_t)(base + t) * NCELL + k];
        if (j == 0) {
            if (i == 0) {
                const float* he = h_ext + (size_t)(base + mm) * HH;
                const float* ce = c_ext + (size_t)(base + mm) * HH;
                #pragma unroll
                for (int s = 0; s < 8; ++s) {
                    int h = hp16 + 16 * s;
                    combH[h * CS + mm] = he[h];
                    combC[h * CS + mm] = ce[h];
                }
            } else {
                #pragma unroll
                for (int s = 0; s < 8; ++s) {
                    int h = hp16 + 16 * s;
                    combH[h * CS + mm] = 0.f;
                    combC[h * CS + mm] = 0.f;
                }
            }
        }
        if (i == 0) {
            #pragma unroll
            for (int s = 0; s < 8; ++s) {
                int h = hp16 + 16 * s;
                combH[(128 + h) * CS + mm] = 0.f;
                combC[(128 + h) * CS + mm] = 0.f;
            }
        } else {
            const float* hr = hrowB + ((size_t)(base + mm) * GWN + j) * HH;
            const float* cr = crowB + ((size_t)(base + mm) * GWN + j) * HH;
            #pragma unroll
            for (int s = 0; s < 8; ++s) {
                int h = hp16 + 16 * s;
                combH[(128 + h) * CS + mm] = hr[h];
                combC[(128 + h) * CS + mm] = cr[h];
            }
        }
        {
            const float* hp = h_g0 + ((size_t)k * BATCH + base + mm) * HH;
            const float* cp = c_g0 + ((size_t)k * BATCH + base + mm) * HH;
            #pragma unroll
            for (int s = 0; s < 8; ++s) {
                int h = hp16 + 16 * s;
                combH[(256 + h) * CS + mm] = hp[h];
                combC[(256 + h) * CS + mm] = cp[h];
            }
        }
        __syncthreads();   // B1: comb/xv built

        // ------------------ pre-LN matmuls (h and c) ------------------
        float aH0[4], aH1[4], aC0[4], aC1[4];
        {
            const float bh0 = bh[k * HH + rs], bh1 = bh[k * HH + rs + 64];
            const float bc0 = bc[k * HH + rs], bc1 = bc[k * HH + rs + 64];
            #pragma unroll
            for (int mi = 0; mi < 4; ++mi) {
                aH0[mi] = bh0; aH1[mi] = bh1; aC0[mi] = bc0; aC1[mi] = bc1;
            }
            const float4* wh4 = (const float4*)whT + (size_t)k * 96 * 128;
            const float4* wc4 = (const float4*)wcT + (size_t)k * 96 * 128;
            #pragma unroll 2
            for (int kb = 0; kb < 96; ++kb) {
                const float4 wh0 = wh4[kb * 128 + rs];
                const float4 wh1 = wh4[kb * 128 + rs + 64];
                const float4 wc0 = wc4[kb * 128 + rs];
                const float4 wc1 = wc4[kb * 128 + rs + 64];
                #pragma unroll
                for (int c = 0; c < 4; ++c) {
                    const float4 ah = *(const float4*)&combH[(4 * kb + c) * CS + m0a];
                    const float4 ac = *(const float4*)&combC[(4 * kb + c) * CS + m0a];
                    const float am[4]  = { ah.x, ah.y, ah.z, ah.w };
                    const float amc[4] = { ac.x, ac.y, ac.z, ac.w };
                    const float w0 = f4c(wh0, c), w1 = f4c(wh1, c);
                    const float w2 = f4c(wc0, c), w3 = f4c(wc1, c);
                    #pragma unroll
                    for (int mi = 0; mi < 4; ++mi) {
                        aH0[mi] += w0 * am[mi];
                        aH1[mi] += w1 * am[mi];
                        aC0[mi] += w2 * amc[mi];
                        aC1[mi] += w3 * amc[mi];
                    }
                }
            }
        }
        __syncthreads();   // B2: all comb reads done, safe to overwrite rows 0..127

        // ------------------ LayerNorm + write ph/pc into comb rows 0..127 ------------------
        {
            #pragma unroll
            for (int mi = 0; mi < 4; ++mi) {
                float s   = aH0[mi] + aH1[mi];
                float sq  = aH0[mi] * aH0[mi] + aH1[mi] * aH1[mi];
                float sc  = aC0[mi] + aC1[mi];
                float sqc = aC0[mi] * aC0[mi] + aC1[mi] * aC1[mi];
                #pragma unroll
                for (int d = 1; d < 64; d <<= 1) {
                    s   += __shfl_xor(s, d);
                    sq  += __shfl_xor(sq, d);
                    sc  += __shfl_xor(sc, d);
                    sqc += __shfl_xor(sqc, d);
                }
                const float muH = s  * (1.f / HH);
                const float rsH = rsq_fast(sq  * (1.f / HH) - muH * muH + EPSF);
                const float muC = sc * (1.f / HH);
                const float rsC = rsq_fast(sqc * (1.f / HH) - muC * muC + EPSF);
                aH0[mi] = (aH0[mi] - muH) * rsH;  aH1[mi] = (aH1[mi] - muH) * rsH;
                aC0[mi] = (aC0[mi] - muC) * rsC;  aC1[mi] = (aC1[mi] - muC) * rsC;
            }
            const float g0  = lnh_g[k * HH + rs], g1  = lnh_g[k * HH + rs + 64];
            const float b0  = lnh_b[k * HH + rs], b1  = lnh_b[k * HH + rs + 64];
            const float gc0 = lnc_g[k * HH + rs], gc1 = lnc_g[k * HH + rs + 64];
            const float bc0 = lnc_b[k * HH + rs], bc1 = lnc_b[k * HH + rs + 64];
            *(float4*)&combH[rs * CS + m0a] =
                make_float4(aH0[0] * g0 + b0, aH0[1] * g0 + b0, aH0[2] * g0 + b0, aH0[3] * g0 + b0);
            *(float4*)&combH[(rs + 64) * CS + m0a] =
                make_float4(aH1[0] * g1 + b1, aH1[1] * g1 + b1, aH1[2] * g1 + b1, aH1[3] * g1 + b1);
            *(float4*)&combC[rs * CS + m0a] =
                make_float4(aC0[0] * gc0 + bc0, aC0[1] * gc0 + bc0, aC0[2] * gc0 + bc0, aC0[3] * gc0 + bc0);
            *(float4*)&combC[(rs + 64) * CS + m0a] =
                make_float4(aC1[0] * gc1 + bc1, aC1[1] * gc1 + bc1, aC1[2] * gc1 + bc1, aC1[3] * gc1 + bc1);
        }
        __syncthreads();   // B3: ph/pc visible

        // ------------------ gates GEMM ------------------
        float ga[4][8];
        {
            float xr[8];
            #pragma unroll
            for (int mi = 0; mi < 8; ++mi) xr[mi] = xv[m0b + mi];
            #pragma unroll
            for (int oi = 0; oi < 4; ++oi) {
                const int o = q + oi * 128;
                const float wih = W_ih[k * 512 + o];
                const float bo  = b_ih[k * 512 + o] + b_hh[k * 512 + o];
                #pragma unroll
                for (int mi = 0; mi < 8; ++mi) ga[oi][mi] = bo + wih * xr[mi];
            }
            const float4* whh4 = (const float4*)whhT + (size_t)k * 32 * 512;
            #pragma unroll 2
            for (int kb = 0; kb < 32; ++kb) {
                const float4 wv0 = whh4[kb * 512 + q];
                const float4 wv1 = whh4[kb * 512 + q + 128];
                const float4 wv2 = whh4[kb * 512 + q + 256];
                const float4 wv3 = whh4[kb * 512 + q + 384];
                #pragma unroll
                for (int c = 0; c < 4; ++c) {
                    const float4 p0 = *(const float4*)&combH[(4 * kb + c) * CS + m0b];
                    const float4 p1 = *(const float4*)&combH[(4 * kb + c) * CS + m0b + 4];
                    const float pa[8] = { p0.x, p0.y, p0.z, p0.w, p1.x, p1.y, p1.z, p1.w };
                    const float u0 = f4c(wv0, c), u1 = f4c(wv1, c);
                    const float u2 = f4c(wv2, c), u3 = f4c(wv3, c);
                    #pragma unroll
                    for (int mi = 0; mi < 8; ++mi) {
                        ga[0][mi] += u0 * pa[mi];
                        ga[1][mi] += u1 * pa[mi];
                        ga[2][mi] += u2 * pa[mi];
                        ga[3][mi] += u3 * pa[mi];
                    }
                }
            }
        }
        __syncthreads();   // B4: all ph reads done, safe to overwrite with h_new

        // ------------------ LSTM pointwise + writeback ------------------
        {
            const float4 pc0 = *(const float4*)&combC[q * CS + m0b];
            const float4 pc1 = *(const float4*)&combC[q * CS + m0b + 4];
            const float pcv[8] = { pc0.x, pc0.y, pc0.z, pc0.w, pc1.x, pc1.y, pc1.z, pc1.w };
            float hn[8], cn[8];
            #pragma unroll
            for (int mi = 0; mi < 8; ++mi) {
                const float cnew = sigm(ga[1][mi]) * pcv[mi] + sigm(ga[0][mi]) * tanh_fast(ga[2][mi]);
                const float hnew = sigm(ga[3][mi]) * tanh_fast(cnew);
                cn[mi] = cnew; hn[mi] = hnew;
            }
            *(float4*)&combH[q * CS + m0b]     = make_float4(hn[0], hn[1], hn[2], hn[3]);
            *(float4*)&combH[q * CS + m0b + 4] = make_float4(hn[4], hn[5], hn[6], hn[7]);
            *(float4*)&combC[q * CS + m0b]     = make_float4(cn[0], cn[1], cn[2], cn[3]);
            *(float4*)&combC[q * CS + m0b + 4] = make_float4(cn[4], cn[5], cn[6], cn[7]);
            if (k == NCELL - 1) {
                #pragma unroll
                for (int mi = 0; mi < 8; ++mi) {
                    const int b = base + m0b + mi;
                    zout[(size_t)b * 256 + q]       = hn[mi] + h_ext[(size_t)b * HH + q];
                    zout[(size_t)b * 256 + 128 + q] = cn[mi] + c_ext[(size_t)b * HH + q];
                }
            } else {
                #pragma unroll
                for (int mi = 0; mi < 8; ++mi) {
                    const int b = base + m0b + mi;
                    hrowB[((size_t)b * GWN + j) * HH + q] = hn[mi];
                    crowB[((size_t)b * GWN + j) * HH + q] = cn[mi];
                }
            }
        }
        __syncthreads();   // B5: h_new/c_new in place before next build
      }
    }
}

// ---------------------------------------------------------------------------
// fc1: y1 = z @ fc1_W^T + b  [4096,256], fused column sum/sumsq atomics
// ---------------------------------------------------------------------------
__global__ __launch_bounds__(256)
void k_fc1(const float* __restrict__ z, const float* __restrict__ W,
           const float* __restrict__ bias, float* __restrict__ y1,
           float* __restrict__ s1, float* __restrict__ q1)
{
    __shared__ float at[256 * 16];  // [k][row]
    const int t   = threadIdx.x;
    const int row = t & 15;
    const int cg  = t >> 4;
    const int rb  = blockIdx.x * 16;
    {
        const float* zr = z + (size_t)(rb + row) * 256 + cg * 16;
        #pragma unroll
        for (int v = 0; v < 4; ++v) {
            const float4 zz = *(const float4*)(zr + v * 4);
            const int kk = cg * 16 + v * 4;
            at[(kk + 0) * 16 + row] = zz.x;
            at[(kk + 1) * 16 + row] = zz.y;
            at[(kk + 2) * 16 + row] = zz.z;
            at[(kk + 3) * 16 + row] = zz.w;
        }
    }
    __syncthreads();
    const int c0 = cg * 16;
    float acc[16];
    #pragma unroll
    for (int c = 0; c < 16; ++c) acc[c] = bias[c0 + c];
    for (int kb = 0; kb < 64; ++kb) {
        const float a0 = at[(4 * kb + 0) * 16 + row];
        const float a1 = at[(4 * kb + 1) * 16 + row];
        const float a2 = at[(4 * kb + 2) * 16 + row];
        const float a3 = at[(4 * kb + 3) * 16 + row];
        #pragma unroll
        for (int c = 0; c < 16; ++c) {
            const float4 wv = *(const float4*)&W[(size_t)(c0 + c) * 256 + 4 * kb];
            acc[c] += a0 * wv.x + a1 * wv.y + a2 * wv.z + a3 * wv.w;
        }
    }
    {
        float* yr = y1 + (size_t)(rb + row) * 256 + c0;
        #pragma unroll
        for (int v = 0; v < 4; ++v)
            *(float4*)(yr + v * 4) = make_float4(acc[4*v], acc[4*v+1], acc[4*v+2], acc[4*v+3]);
    }
    #pragma unroll
    for (int c = 0; c < 16; ++c) {
        float s = acc[c], sq = acc[c] * acc[c];
        s += __shfl_xor(s, 1); sq += __shfl_xor(sq, 1);
        s += __shfl_xor(s, 2); sq += __shfl_xor(sq, 2);
        s += __shfl_xor(s, 4); sq += __shfl_xor(sq, 4);
        s += __shfl_xor(s, 8); sq += __shfl_xor(sq, 8);
        if (row == 0) { atomicAdd(&s1[c0 + c], s); atomicAdd(&q1[c0 + c], sq); }
    }
}

// ---------------------------------------------------------------------------
// fc2: y2 = relu(bn1(y1)) @ fc2_W^T + b  [4096,128], fused stats
// ---------------------------------------------------------------------------
__global__ __launch_bounds__(256)
void k_fc2(const float* __restrict__ y1, const float* __restrict__ W,
           const float* __restrict__ bias,
           const float* __restrict__ s1, const float* __restrict__ q1,
           const float* __restrict__ g1, const float* __restrict__ b1,
           float* __restrict__ y2, float* __restrict__ s2, float* __restrict__ q2)
{
    __shared__ float at[256 * 16];
    __shared__ float scale[256], shift[256];
    const int t = threadIdx.x;
    {
        const float mu  = s1[t] * (1.f / BATCH);
        const float var = q1[t] * (1.f / BATCH) - mu * mu;
        const float sc  = g1[t] * rsq_fast(var + EPSF);
        scale[t] = sc;
        shift[t] = b1[t] - mu * sc;
    }
    __syncthreads();
    const int row = t & 15;
    const int cg  = t >> 4;
    const int rb  = blockIdx.x * 16;
    {
        const float* yr = y1 + (size_t)(rb + row) * 256 + cg * 16;
        #pragma unroll
        for (int v = 0; v < 4; ++v) {
            const float4 zz = *(const float4*)(yr + v * 4);
            const int kk = cg * 16 + v * 4;
            at[(kk + 0) * 16 + row] = fmaxf(zz.x * scale[kk + 0] + shift[kk + 0], 0.f);
            at[(kk + 1) * 16 + row] = fmaxf(zz.y * scale[kk + 1] + shift[kk + 1], 0.f);
            at[(kk + 2) * 16 + row] = fmaxf(zz.z * scale[kk + 2] + shift[kk + 2], 0.f);
            at[(kk + 3) * 16 + row] = fmaxf(zz.w * scale[kk + 3] + shift[kk + 3], 0.f);
        }
    }
    __syncthreads();
    const int c0 = cg * 8;
    float acc[8];
    #pragma unroll
    for (int c = 0; c < 8; ++c) acc[c] = bias[c0 + c];
    for (int kb = 0; kb < 64; ++kb) {
        const float a0 = at[(4 * kb + 0) * 16 + row];
        const float a1 = at[(4 * kb + 1) * 16 + row];
        const float a2 = at[(4 * kb + 2) * 16 + row];
        const float a3 = at[(4 * kb + 3) * 16 + row];
        #pragma unroll
        for (int c = 0; c < 8; ++c) {
            const float4 wv = *(const float4*)&W[(size_t)(c0 + c) * 256 + 4 * kb];
            acc[c] += a0 * wv.x + a1 * wv.y + a2 * wv.z + a3 * wv.w;
        }
    }
    {
        float* yr = y2 + (size_t)(rb + row) * 128 + c0;
        *(float4*)(yr)     = make_float4(acc[0], acc[1], acc[2], acc[3]);
        *(float4*)(yr + 4) = make_float4(acc[4], acc[5], acc[6], acc[7]);
    }
    #pragma unroll
    for (int c = 0; c < 8; ++c) {
        float s = acc[c], sq = acc[c] * acc[c];
        s += __shfl_xor(s, 1); sq += __shfl_xor(sq, 1);
        s += __shfl_xor(s, 2); sq += __shfl_xor(sq, 2);
        s += __shfl_xor(s, 4); sq += __shfl_xor(sq, 4);
        s += __shfl_xor(s, 8); sq += __shfl_xor(sq, 8);
        if (row == 0) { atomicAdd(&s2[c0 + c], s); atomicAdd(&q2[c0 + c], sq); }
    }
}

// ---------------------------------------------------------------------------
// fc3: y3 = relu(bn2(y2)) @ fc3_W^T + b  [4096,1], fused scalar stats
// ---------------------------------------------------------------------------
__global__ __launch_bounds__(256)
void k_fc3(const float* __restrict__ y2, const float* __restrict__ W3,
           const float* __restrict__ b3,
           const float* __restrict__ s2, const float* __restrict__ q2,
           const float* __restrict__ g2, const float* __restrict__ b2,
           float* __restrict__ y3, float* __restrict__ s3, float* __restrict__ q3)
{
    __shared__ float scale[128], shift[128], w3s[128];
    const int t = threadIdx.x;
    if (t < 128) {
        const float mu  = s2[t] * (1.f / BATCH);
        const float var = q2[t] * (1.f / BATCH) - mu * mu;
        const float sc  = g2[t] * rsq_fast(var + EPSF);
        scale[t] = sc;
        shift[t] = b2[t] - mu * sc;
        w3s[t]   = W3[t];
    }
    __syncthreads();
    const int r = blockIdx.x * 256 + t;
    float acc = b3[0];
    const float* yr = y2 + (size_t)r * 128;
    for (int kb = 0; kb < 32; ++kb) {
        const float4 v = *(const float4*)(yr + 4 * kb);
        const int kk = 4 * kb;
        acc += fmaxf(v.x * scale[kk + 0] + shift[kk + 0], 0.f) * w3s[kk + 0];
        acc += fmaxf(v.y * scale[kk + 1] + shift[kk + 1], 0.f) * w3s[kk + 1];
        acc += fmaxf(v.z * scale[kk + 2] + shift[kk + 2], 0.f) * w3s[kk + 2];
        acc += fmaxf(v.w * scale[kk + 3] + shift[kk + 3], 0.f) * w3s[kk + 3];
    }
    y3[r] = acc;
    float s = acc, sq = acc * acc;
    #pragma unroll
    for (int d = 1; d < 64; d <<= 1) { s += __shfl_xor(s, d); sq += __shfl_xor(sq, d); }
    if ((t & 63) == 0) { atomicAdd(&s3[0], s); atomicAdd(&q3[0], sq); }
}

// ---------------------------------------------------------------------------
// out = sigmoid(bn_out(y3))
// ---------------------------------------------------------------------------
__global__ __launch_bounds__(256)
void k_out(const float* __restrict__ y3,
           const float* __restrict__ s3, const float* __restrict__ q3,
           const float* __restrict__ g, const float* __restrict__ b,
           float* __restrict__ out)
{
    const int r = blockIdx.x * 256 + threadIdx.x;
    const float mu  = s3[0] * (1.f / BATCH);
    const float var = q3[0] * (1.f / BATCH) - mu * mu;
    const float sc  = g[0] * rsq_fast(var + EPSF);
    out[r] = sigm((y3[r] - mu) * sc + b[0]);
}

// ---------------------------------------------------------------------------
extern "C" void kernel_launch(void* const* d_in, const int* in_sizes, int n_in,
                              void* d_out, int out_size, void* d_ws, size_t ws_size,
                              hipStream_t stream)
{
    const float* x     = (const float*)d_in[0];
    const float* h_ext = (const float*)d_in[1];
    const float* c_ext = (const float*)d_in[2];
    const float* h_g0  = (const float*)d_in[3];
    const float* c_g0  = (const float*)d_in[4];
    const float* Wh    = (const float*)d_in[5];
    const float* bh    = (const float*)d_in[6];
    const float* Wc    = (const float*)d_in[7];
    const float* bc    = (const float*)d_in[8];
    const float* lnh_g = (const float*)d_in[9];
    const float* lnh_b = (const float*)d_in[10];
    const float* lnc_g = (const float*)d_in[11];
    const float* lnc_b = (const float*)d_in[12];
    const float* W_ih  = (const float*)d_in[13];
    const float* b_ih  = (const float*)d_in[14];
    const float* W_hh  = (const float*)d_in[15];
    const float* b_hh  = (const float*)d_in[16];
    const float* fc1_W = (const float*)d_in[17];
    const float* fc1_b = (const float*)d_in[18];
    const float* bn1_g = (const float*)d_in[19];
    const float* bn1_b = (const float*)d_in[20];
    const float* fc2_W = (const float*)d_in[21];
    const float* fc2_b = (const float*)d_in[22];
    const float* bn2_g = (const float*)d_in[23];
    const float* bn2_b = (const float*)d_in[24];
    const float* fc3_W = (const float*)d_in[25];
    const float* fc3_b = (const float*)d_in[26];
    const float* bno_g = (const float*)d_in[27];
    const float* bno_b = (const float*)d_in[28];

    float* ws   = (float*)d_ws;
    float* whT  = ws;                        // 81*96*128*4 = 3,981,312
    float* wcT  = whT  + 3981312;
    float* whhT = wcT  + 3981312;            // 81*32*512*4 = 5,308,416
    float* hrow = whhT + 5308416;            // 4096*9*128  = 4,718,592
    float* crow = hrow + 4718592;
    float* z    = crow + 4718592;            // 4096*256 = 1,048,576
    float* y1   = z    + 1048576;            // 1,048,576
    float* y2   = y1   + 1048576;            // 524,288
    float* y3   = y2   + 524288;             // 4,096
    float* st   = y3   + 4096;               // 770 stats floats
    float* s1 = st;        float* q1 = s1 + 256;
    float* s2 = q1 + 256;  float* q2 = s2 + 128;
    float* s3 = q2 + 128;  float* q3 = s3 + 1;

    hipMemsetAsync(st, 0, 770 * sizeof(float), stream);
    hipLaunchKernelGGL(k_transpose, dim3(1024), dim3(256), 0, stream,
                       Wh, Wc, W_hh, whT, wcT, whhT);
    hipLaunchKernelGGL(k_lattice, dim3(NBLK), dim3(256), 0, stream,
                       x, h_ext, c_ext, h_g0, c_g0, whT, wcT, whhT, bh, bc,
                       lnh_g, lnh_b, lnc_g, lnc_b, W_ih, b_ih, b_hh, hrow, crow, z);
    hipLaunchKernelGGL(k_fc1, dim3(256), dim3(256), 0, stream, z, fc1_W, fc1_b, y1, s1, q1);
    hipLaunchKernelGGL(k_fc2, dim3(256), dim3(256), 0, stream,
                       y1, fc2_W, fc2_b, s1, q1, bn1_g, bn1_b, y2, s2, q2);
    hipLaunchKernelGGL(k_fc3, dim3(16), dim3(256), 0, stream,
                       y2, fc3_W, fc3_b, s2, q2, bn2_g, bn2_b, y3, s3, q3);
    hipLaunchKernelGGL(k_out, dim3(16), dim3(256), 0, stream,
                       y3, s3, q3, bno_g, bno_b, (float*)d_out);
}